// Round 1
// baseline (403.393 us; speedup 1.0000x reference)
//
#include <hip/hip_runtime.h>

// MultiHeadAttention: B=2,S=2048,D=1024,H=16,dh=64. fp32 in/out, bf16 MFMA internally.
// Pipeline: convert x -> bf16 ; transpose w_qkv,w_proj -> bf16 B^T ; QKV GEMM (MFMA,
// epilogue scatters per-head Q/K/V + bias) ; transpose V -> V^T ; flash attention
// (online softmax + causal + forcing reweight) ; proj GEMM (MFMA, fp32 out + bias).
// Workspace: 48 MB.

typedef __attribute__((ext_vector_type(8))) short short8;
typedef __attribute__((ext_vector_type(4))) float f32x4;

#define MFMA_B16(a, b, c) __builtin_amdgcn_mfma_f32_16x16x32_bf16(a, b, c, 0, 0, 0)

static __device__ __forceinline__ unsigned short f2bf(float f) {
    union { float f; unsigned int u; } v;
    v.f = f;
    unsigned int r = (v.u + 0x7fffu + ((v.u >> 16) & 1u)) >> 16;
    return (unsigned short)r;
}

// ---------------- convert x (fp32 -> bf16), 4 elems/thread ----------------
__global__ __launch_bounds__(256) void convert_x_kernel(const float4* __restrict__ x,
                                                        ushort4* __restrict__ xb) {
    int i = blockIdx.x * 256 + threadIdx.x;  // 1048576 float4s
    float4 v = x[i];
    ushort4 o;
    o.x = f2bf(v.x); o.y = f2bf(v.y); o.z = f2bf(v.z); o.w = f2bf(v.w);
    xb[i] = o;
}

// ------------- transpose+convert: in fp32 [R][C] -> out bf16 [C][R] -------------
__global__ __launch_bounds__(256) void transpose_cvt_kernel(const float* __restrict__ in,
                                                            unsigned short* __restrict__ out,
                                                            int R, int C) {
    __shared__ float t[32][33];
    int c0 = blockIdx.x * 32, r0 = blockIdx.y * 32;
    int x = threadIdx.x, y = threadIdx.y;
    #pragma unroll
    for (int yy = y; yy < 32; yy += 8)
        t[yy][x] = in[(size_t)(r0 + yy) * C + (c0 + x)];
    __syncthreads();
    #pragma unroll
    for (int yy = y; yy < 32; yy += 8)
        out[(size_t)(c0 + yy) * R + (r0 + x)] = f2bf(t[x][yy]);
}

// ------------- transpose V: [32 bh][2048 s][64 d] bf16 -> [32 bh][64 d][2048 s] -------------
__global__ __launch_bounds__(256) void transpose_v_kernel(const unsigned short* __restrict__ v,
                                                          unsigned short* __restrict__ vT) {
    __shared__ unsigned short t[32][33];
    int d0 = blockIdx.x * 32, s0 = blockIdx.y * 32, bh = blockIdx.z;
    const unsigned short* vb = v + (size_t)bh * 2048 * 64;
    unsigned short* vTb = vT + (size_t)bh * 2048 * 64;
    int x = threadIdx.x, y = threadIdx.y;
    #pragma unroll
    for (int yy = y; yy < 32; yy += 8)
        t[yy][x] = vb[(s0 + yy) * 64 + d0 + x];
    __syncthreads();
    #pragma unroll
    for (int yy = y; yy < 32; yy += 8)
        vTb[(d0 + yy) * 2048 + s0 + x] = t[x][yy];
}

// ---------------- QKV GEMM: C[4096x3072] = A[4096x1024] * Bt[3072x1024]^T ----------------
// 128x128 tile, 4 waves (2x2) of 64x64, BK=32. Epilogue scatters per-head + bias.
__global__ __launch_bounds__(256) void gemm_qkv_kernel(const unsigned short* __restrict__ A,
                                                       const unsigned short* __restrict__ Bt,
                                                       const float* __restrict__ bias,
                                                       unsigned short* __restrict__ q,
                                                       unsigned short* __restrict__ k,
                                                       unsigned short* __restrict__ v) {
    __shared__ unsigned short As[128][40];  // pad to 40 (80 B stride) to break bank conflicts
    __shared__ unsigned short Bs[128][40];
    const int tid = threadIdx.x;
    const int lane = tid & 63, wave = tid >> 6;
    const int l15 = lane & 15, quad = lane >> 4;
    const int wm = wave >> 1, wn = wave & 1;
    const int row0 = blockIdx.y * 128, col0 = blockIdx.x * 128;
    const int K = 1024;

    f32x4 acc[4][4] = {};

    for (int kt = 0; kt < K; kt += 32) {
        #pragma unroll
        for (int h = 0; h < 2; ++h) {
            int c = tid + h * 256;
            int r = c >> 2, seg = (c & 3) * 8;
            *(uint4*)&As[r][seg] = *(const uint4*)&A[(size_t)(row0 + r) * K + kt + seg];
            *(uint4*)&Bs[r][seg] = *(const uint4*)&Bt[(size_t)(col0 + r) * K + kt + seg];
        }
        __syncthreads();
        short8 af[4], bf[4];
        #pragma unroll
        for (int i = 0; i < 4; ++i) af[i] = *(const short8*)&As[wm * 64 + i * 16 + l15][quad * 8];
        #pragma unroll
        for (int j = 0; j < 4; ++j) bf[j] = *(const short8*)&Bs[wn * 64 + j * 16 + l15][quad * 8];
        #pragma unroll
        for (int i = 0; i < 4; ++i)
            #pragma unroll
            for (int j = 0; j < 4; ++j)
                acc[i][j] = MFMA_B16(af[i], bf[j], acc[i][j]);
        __syncthreads();
    }

    #pragma unroll
    for (int i = 0; i < 4; ++i)
        #pragma unroll
        for (int j = 0; j < 4; ++j)
            #pragma unroll
            for (int r = 0; r < 4; ++r) {
                int row = row0 + wm * 64 + i * 16 + quad * 4 + r;  // b*2048+s
                int col = col0 + wn * 64 + j * 16 + l15;           // which*1024+h*64+d
                float val = acc[i][j][r] + bias[col];
                int which = col >> 10, rem = col & 1023;
                int hh = rem >> 6, d = rem & 63;
                int b = row >> 11, s = row & 2047;
                size_t o = ((size_t)((b * 16 + hh) * 2048 + s)) * 64 + d;
                unsigned short bv = f2bf(val);
                if (which == 0) q[o] = bv;
                else if (which == 1) k[o] = bv;
                else v[o] = bv;
            }
}

// ---------------- proj GEMM: out[4096x1024] fp32 = A[4096x1024] * Bt[1024x1024]^T + bias ----------------
__global__ __launch_bounds__(256) void gemm_proj_kernel(const unsigned short* __restrict__ A,
                                                        const unsigned short* __restrict__ Bt,
                                                        const float* __restrict__ bias,
                                                        float* __restrict__ out) {
    __shared__ unsigned short As[128][40];
    __shared__ unsigned short Bs[128][40];
    const int tid = threadIdx.x;
    const int lane = tid & 63, wave = tid >> 6;
    const int l15 = lane & 15, quad = lane >> 4;
    const int wm = wave >> 1, wn = wave & 1;
    const int row0 = blockIdx.y * 128, col0 = blockIdx.x * 128;
    const int K = 1024;

    f32x4 acc[4][4] = {};

    for (int kt = 0; kt < K; kt += 32) {
        #pragma unroll
        for (int h = 0; h < 2; ++h) {
            int c = tid + h * 256;
            int r = c >> 2, seg = (c & 3) * 8;
            *(uint4*)&As[r][seg] = *(const uint4*)&A[(size_t)(row0 + r) * K + kt + seg];
            *(uint4*)&Bs[r][seg] = *(const uint4*)&Bt[(size_t)(col0 + r) * K + kt + seg];
        }
        __syncthreads();
        short8 af[4], bf[4];
        #pragma unroll
        for (int i = 0; i < 4; ++i) af[i] = *(const short8*)&As[wm * 64 + i * 16 + l15][quad * 8];
        #pragma unroll
        for (int j = 0; j < 4; ++j) bf[j] = *(const short8*)&Bs[wn * 64 + j * 16 + l15][quad * 8];
        #pragma unroll
        for (int i = 0; i < 4; ++i)
            #pragma unroll
            for (int j = 0; j < 4; ++j)
                acc[i][j] = MFMA_B16(af[i], bf[j], acc[i][j]);
        __syncthreads();
    }

    #pragma unroll
    for (int i = 0; i < 4; ++i)
        #pragma unroll
        for (int j = 0; j < 4; ++j)
            #pragma unroll
            for (int r = 0; r < 4; ++r) {
                int row = row0 + wm * 64 + i * 16 + quad * 4 + r;
                int col = col0 + wn * 64 + j * 16 + l15;
                out[(size_t)row * 1024 + col] = acc[i][j][r] + bias[col];
            }
}

// ---------------- flash attention, causal + forcing reweight ----------------
// 1 wave = 16 q-rows; key blocks of 32; Q/K row-major [bh][s][64], V^T [bh][64][s].
__global__ __launch_bounds__(256) void attn_kernel(const unsigned short* __restrict__ Q,
                                                   const unsigned short* __restrict__ Kb,
                                                   const unsigned short* __restrict__ Vt,
                                                   const int* __restrict__ idx,
                                                   const float* __restrict__ weight,
                                                   const int* __restrict__ forcing,
                                                   unsigned short* __restrict__ O) {
    __shared__ unsigned short Plds[4][16][40];  // per-wave P round-trip (C-layout -> A-layout)
    const int tid = threadIdx.x;
    const int lane = tid & 63, wave = tid >> 6;
    const int l15 = lane & 15, quad = lane >> 4;
    const int bid = blockIdx.x;
    const int tileq = bid & 31, bh = bid >> 5;
    const int b = bh >> 4, hh = bh & 15;
    const int q0 = tileq * 64 + wave * 16;
    const unsigned short* Qb = Q + (size_t)bh * 2048 * 64;
    const unsigned short* Kh = Kb + (size_t)bh * 2048 * 64;
    const unsigned short* Vh = Vt + (size_t)bh * 2048 * 64;

    const int idxb = idx[b];
    const float wgt = (forcing[0] != 0) ? weight[0] : 1.0f;

    short8 aq0 = *(const short8*)&Qb[(q0 + l15) * 64 + quad * 8];
    short8 aq1 = *(const short8*)&Qb[(q0 + l15) * 64 + 32 + quad * 8];

    float m[4], l[4];
    f32x4 o[4] = {};
    #pragma unroll
    for (int r = 0; r < 4; ++r) { m[r] = -3.0e38f; l[r] = 0.0f; }

    const int nkb = (q0 + 16 + 31) >> 5;  // ceil((q0+16)/32) key blocks (causal)
    for (int kb = 0; kb < nkb; ++kb) {
        const int kbase = kb * 32;
        short8 bk0a = *(const short8*)&Kh[(kbase + l15) * 64 + quad * 8];
        short8 bk0b = *(const short8*)&Kh[(kbase + l15) * 64 + 32 + quad * 8];
        short8 bk1a = *(const short8*)&Kh[(kbase + 16 + l15) * 64 + quad * 8];
        short8 bk1b = *(const short8*)&Kh[(kbase + 16 + l15) * 64 + 32 + quad * 8];
        f32x4 s0 = {}, s1 = {};
        s0 = MFMA_B16(aq0, bk0a, s0);
        s0 = MFMA_B16(aq1, bk0b, s0);
        s1 = MFMA_B16(aq0, bk1a, s1);
        s1 = MFMA_B16(aq1, bk1b, s1);

        const int kc0 = kbase + l15, kc1 = kbase + 16 + l15;
        const float af0 = (kc0 >= idxb) ? wgt : 1.0f;
        const float af1 = (kc1 >= idxb) ? wgt : 1.0f;
        float p0[4], p1[4], alpha[4];
        #pragma unroll
        for (int r = 0; r < 4; ++r) {
            const int qr = q0 + quad * 4 + r;
            float v0 = s0[r] * 0.125f; if (kc0 > qr) v0 = -3.0e38f;
            float v1 = s1[r] * 0.125f; if (kc1 > qr) v1 = -3.0e38f;
            float mm = fmaxf(v0, v1);
            mm = fmaxf(mm, __shfl_xor(mm, 1));
            mm = fmaxf(mm, __shfl_xor(mm, 2));
            mm = fmaxf(mm, __shfl_xor(mm, 4));
            mm = fmaxf(mm, __shfl_xor(mm, 8));
            const float mnew = fmaxf(m[r], mm);
            alpha[r] = __expf(m[r] - mnew);
            m[r] = mnew;
            v0 = __expf(v0 - mnew) * af0;
            v1 = __expf(v1 - mnew) * af1;
            p0[r] = v0; p1[r] = v1;
            float rs = v0 + v1;
            rs += __shfl_xor(rs, 1);
            rs += __shfl_xor(rs, 2);
            rs += __shfl_xor(rs, 4);
            rs += __shfl_xor(rs, 8);
            l[r] = l[r] * alpha[r] + rs;
        }
        #pragma unroll
        for (int d = 0; d < 4; ++d) {
            f32x4 t = o[d];
            #pragma unroll
            for (int r = 0; r < 4; ++r) t[r] *= alpha[r];
            o[d] = t;
        }
        #pragma unroll
        for (int r = 0; r < 4; ++r) {
            Plds[wave][quad * 4 + r][l15] = f2bf(p0[r]);
            Plds[wave][quad * 4 + r][16 + l15] = f2bf(p1[r]);
        }
        short8 ap = *(const short8*)&Plds[wave][l15][quad * 8];
        #pragma unroll
        for (int d = 0; d < 4; ++d) {
            short8 bv = *(const short8*)&Vh[(d * 16 + l15) * 2048 + kbase + quad * 8];
            o[d] = MFMA_B16(ap, bv, o[d]);
        }
    }

    #pragma unroll
    for (int r = 0; r < 4; ++r) {
        const int s = q0 + quad * 4 + r;
        const float inv = 1.0f / l[r];
        const size_t rowoff = ((size_t)(b * 2048 + s)) * 1024 + hh * 64;
        #pragma unroll
        for (int d = 0; d < 4; ++d)
            O[rowoff + d * 16 + l15] = f2bf(o[d][r] * inv);
    }
}

extern "C" void kernel_launch(void* const* d_in, const int* in_sizes, int n_in,
                              void* d_out, int out_size, void* d_ws, size_t ws_size,
                              hipStream_t stream) {
    const float* x        = (const float*)d_in[0];   // [2,2048,1024]
    const int*   idx      = (const int*)d_in[1];     // [2]
    const float* weight   = (const float*)d_in[2];   // [1]
    const int*   forcing  = (const int*)d_in[3];     // [1]
    const float* w_qkv    = (const float*)d_in[4];   // [1024,3072]
    const float* b_qkv    = (const float*)d_in[5];   // [3072]
    const float* w_proj   = (const float*)d_in[6];   // [1024,1024]
    const float* b_proj   = (const float*)d_in[7];   // [1024]
    float* out = (float*)d_out;

    char* ws = (char*)d_ws;
    unsigned short* xb      = (unsigned short*)(ws);                   // 8388608 B (also attn_out later)
    unsigned short* wqkvT   = (unsigned short*)(ws + 8388608);         // 6291456 B
    unsigned short* wprojT  = (unsigned short*)(ws + 14680064);        // 2097152 B
    unsigned short* qbuf    = (unsigned short*)(ws + 16777216);        // 8388608 B
    unsigned short* kbuf    = (unsigned short*)(ws + 25165824);        // 8388608 B
    unsigned short* vbuf    = (unsigned short*)(ws + 33554432);        // 8388608 B
    unsigned short* vTbuf   = (unsigned short*)(ws + 41943040);        // 8388608 B  (total 48 MB)
    unsigned short* attn_out = xb;  // xb is dead after gemm_qkv

    convert_x_kernel<<<4096, 256, 0, stream>>>((const float4*)x, (ushort4*)xb);
    transpose_cvt_kernel<<<dim3(96, 32), dim3(32, 8), 0, stream>>>(w_qkv, wqkvT, 1024, 3072);
    transpose_cvt_kernel<<<dim3(32, 32), dim3(32, 8), 0, stream>>>(w_proj, wprojT, 1024, 1024);
    gemm_qkv_kernel<<<dim3(24, 32), 256, 0, stream>>>(xb, wqkvT, b_qkv, qbuf, kbuf, vbuf);
    transpose_v_kernel<<<dim3(2, 64, 32), dim3(32, 8), 0, stream>>>(vbuf, vTbuf);
    attn_kernel<<<1024, 256, 0, stream>>>(qbuf, kbuf, vTbuf, idx, weight, forcing, attn_out);
    gemm_proj_kernel<<<dim3(8, 32), 256, 0, stream>>>(attn_out, wprojT, b_proj, out);
}

// Round 2
// 256.320 us; speedup vs baseline: 1.5738x; 1.5738x over previous
//
#include <hip/hip_runtime.h>

// MultiHeadAttention: B=2,S=2048,D=1024,H=16,dh=64. fp32 in/out, bf16 MFMA internally.
// R2: attention rewritten — paired q-tiles (t,31-t) for perfect balance, 64-key blocks,
// K/V staged in LDS via global_load_lds (XOR-swizzled), double-buffered prefetch.

typedef __attribute__((ext_vector_type(8))) short short8;
typedef __attribute__((ext_vector_type(4))) float f32x4;

#define MFMA_B16(a, b, c) __builtin_amdgcn_mfma_f32_16x16x32_bf16(a, b, c, 0, 0, 0)

static __device__ __forceinline__ unsigned short f2bf(float f) {
    union { float f; unsigned int u; } v;
    v.f = f;
    unsigned int r = (v.u + 0x7fffu + ((v.u >> 16) & 1u)) >> 16;
    return (unsigned short)r;
}

static __device__ __forceinline__ void gl_lds16(const void* g, void* l) {
    __builtin_amdgcn_global_load_lds(
        (const __attribute__((address_space(1))) unsigned int*)g,
        (__attribute__((address_space(3))) unsigned int*)l, 16, 0, 0);
}

// ---------------- convert x (fp32 -> bf16), 4 elems/thread ----------------
__global__ __launch_bounds__(256) void convert_x_kernel(const float4* __restrict__ x,
                                                        ushort4* __restrict__ xb) {
    int i = blockIdx.x * 256 + threadIdx.x;  // 1048576 float4s
    float4 v = x[i];
    ushort4 o;
    o.x = f2bf(v.x); o.y = f2bf(v.y); o.z = f2bf(v.z); o.w = f2bf(v.w);
    xb[i] = o;
}

// ------------- transpose+convert: in fp32 [R][C] -> out bf16 [C][R] -------------
__global__ __launch_bounds__(256) void transpose_cvt_kernel(const float* __restrict__ in,
                                                            unsigned short* __restrict__ out,
                                                            int R, int C) {
    __shared__ float t[32][33];
    int c0 = blockIdx.x * 32, r0 = blockIdx.y * 32;
    int x = threadIdx.x, y = threadIdx.y;
    #pragma unroll
    for (int yy = y; yy < 32; yy += 8)
        t[yy][x] = in[(size_t)(r0 + yy) * C + (c0 + x)];
    __syncthreads();
    #pragma unroll
    for (int yy = y; yy < 32; yy += 8)
        out[(size_t)(c0 + yy) * R + (r0 + x)] = f2bf(t[x][yy]);
}

// ------------- transpose V: [32 bh][2048 s][64 d] bf16 -> [32 bh][64 d][2048 s] -------------
__global__ __launch_bounds__(256) void transpose_v_kernel(const unsigned short* __restrict__ v,
                                                          unsigned short* __restrict__ vT) {
    __shared__ unsigned short t[32][33];
    int d0 = blockIdx.x * 32, s0 = blockIdx.y * 32, bh = blockIdx.z;
    const unsigned short* vb = v + (size_t)bh * 2048 * 64;
    unsigned short* vTb = vT + (size_t)bh * 2048 * 64;
    int x = threadIdx.x, y = threadIdx.y;
    #pragma unroll
    for (int yy = y; yy < 32; yy += 8)
        t[yy][x] = vb[(s0 + yy) * 64 + d0 + x];
    __syncthreads();
    #pragma unroll
    for (int yy = y; yy < 32; yy += 8)
        vTb[(d0 + yy) * 2048 + s0 + x] = t[x][yy];
}

// ---------------- QKV GEMM: C[4096x3072] = A[4096x1024] * Bt[3072x1024]^T ----------------
__global__ __launch_bounds__(256) void gemm_qkv_kernel(const unsigned short* __restrict__ A,
                                                       const unsigned short* __restrict__ Bt,
                                                       const float* __restrict__ bias,
                                                       unsigned short* __restrict__ q,
                                                       unsigned short* __restrict__ k,
                                                       unsigned short* __restrict__ v) {
    __shared__ unsigned short As[128][40];
    __shared__ unsigned short Bs[128][40];
    const int tid = threadIdx.x;
    const int lane = tid & 63, wave = tid >> 6;
    const int l15 = lane & 15, quad = lane >> 4;
    const int wm = wave >> 1, wn = wave & 1;
    const int row0 = blockIdx.y * 128, col0 = blockIdx.x * 128;
    const int K = 1024;

    f32x4 acc[4][4] = {};

    for (int kt = 0; kt < K; kt += 32) {
        #pragma unroll
        for (int h = 0; h < 2; ++h) {
            int c = tid + h * 256;
            int r = c >> 2, seg = (c & 3) * 8;
            *(uint4*)&As[r][seg] = *(const uint4*)&A[(size_t)(row0 + r) * K + kt + seg];
            *(uint4*)&Bs[r][seg] = *(const uint4*)&Bt[(size_t)(col0 + r) * K + kt + seg];
        }
        __syncthreads();
        short8 af[4], bf[4];
        #pragma unroll
        for (int i = 0; i < 4; ++i) af[i] = *(const short8*)&As[wm * 64 + i * 16 + l15][quad * 8];
        #pragma unroll
        for (int j = 0; j < 4; ++j) bf[j] = *(const short8*)&Bs[wn * 64 + j * 16 + l15][quad * 8];
        #pragma unroll
        for (int i = 0; i < 4; ++i)
            #pragma unroll
            for (int j = 0; j < 4; ++j)
                acc[i][j] = MFMA_B16(af[i], bf[j], acc[i][j]);
        __syncthreads();
    }

    #pragma unroll
    for (int i = 0; i < 4; ++i)
        #pragma unroll
        for (int j = 0; j < 4; ++j)
            #pragma unroll
            for (int r = 0; r < 4; ++r) {
                int row = row0 + wm * 64 + i * 16 + quad * 4 + r;
                int col = col0 + wn * 64 + j * 16 + l15;
                float val = acc[i][j][r] + bias[col];
                int which = col >> 10, rem = col & 1023;
                int hh = rem >> 6, d = rem & 63;
                int b = row >> 11, s = row & 2047;
                size_t o = ((size_t)((b * 16 + hh) * 2048 + s)) * 64 + d;
                unsigned short bv = f2bf(val);
                if (which == 0) q[o] = bv;
                else if (which == 1) k[o] = bv;
                else v[o] = bv;
            }
}

// ---------------- proj GEMM: out[4096x1024] fp32 = A[4096x1024] * Bt[1024x1024]^T + bias ----------------
__global__ __launch_bounds__(256) void gemm_proj_kernel(const unsigned short* __restrict__ A,
                                                        const unsigned short* __restrict__ Bt,
                                                        const float* __restrict__ bias,
                                                        float* __restrict__ out) {
    __shared__ unsigned short As[128][40];
    __shared__ unsigned short Bs[128][40];
    const int tid = threadIdx.x;
    const int lane = tid & 63, wave = tid >> 6;
    const int l15 = lane & 15, quad = lane >> 4;
    const int wm = wave >> 1, wn = wave & 1;
    const int row0 = blockIdx.y * 128, col0 = blockIdx.x * 128;
    const int K = 1024;

    f32x4 acc[4][4] = {};

    for (int kt = 0; kt < K; kt += 32) {
        #pragma unroll
        for (int h = 0; h < 2; ++h) {
            int c = tid + h * 256;
            int r = c >> 2, seg = (c & 3) * 8;
            *(uint4*)&As[r][seg] = *(const uint4*)&A[(size_t)(row0 + r) * K + kt + seg];
            *(uint4*)&Bs[r][seg] = *(const uint4*)&Bt[(size_t)(col0 + r) * K + kt + seg];
        }
        __syncthreads();
        short8 af[4], bf[4];
        #pragma unroll
        for (int i = 0; i < 4; ++i) af[i] = *(const short8*)&As[wm * 64 + i * 16 + l15][quad * 8];
        #pragma unroll
        for (int j = 0; j < 4; ++j) bf[j] = *(const short8*)&Bs[wn * 64 + j * 16 + l15][quad * 8];
        #pragma unroll
        for (int i = 0; i < 4; ++i)
            #pragma unroll
            for (int j = 0; j < 4; ++j)
                acc[i][j] = MFMA_B16(af[i], bf[j], acc[i][j]);
        __syncthreads();
    }

    #pragma unroll
    for (int i = 0; i < 4; ++i)
        #pragma unroll
        for (int j = 0; j < 4; ++j)
            #pragma unroll
            for (int r = 0; r < 4; ++r) {
                int row = row0 + wm * 64 + i * 16 + quad * 4 + r;
                int col = col0 + wn * 64 + j * 16 + l15;
                out[(size_t)row * 1024 + col] = acc[i][j][r] + bias[col];
            }
}

// ---------------- flash attention R2 ----------------
// Block = 4 waves, processes q-tiles t and 31-t (64 rows each; wave w owns 16 rows).
// Per 64-key iteration: K tile (64x64) and V^T tile (64x64) staged in LDS via
// global_load_lds with XOR swizzle; double-buffered prefetch; one barrier/iter.
__global__ __launch_bounds__(256) void attn_kernel(const unsigned short* __restrict__ Q,
                                                   const unsigned short* __restrict__ Kg,
                                                   const unsigned short* __restrict__ Vt,
                                                   const int* __restrict__ idx,
                                                   const float* __restrict__ weight,
                                                   const int* __restrict__ forcing,
                                                   unsigned short* __restrict__ O) {
    __shared__ unsigned short Ks[2][64 * 64];   // [buf][row*64 + slot*8 + e]
    __shared__ unsigned short Vs[2][64 * 64];   // [buf][d*64 + slot*8 + e]
    __shared__ unsigned short Plds[4][16 * 68]; // per-wave P roundtrip, stride 68

    const int tid = threadIdx.x;
    const int lane = tid & 63, wave = tid >> 6;
    const int l15 = lane & 15, quad = lane >> 4;
    const int bid = blockIdx.x;
    const int p = bid & 15, bh = bid >> 4;
    const int b = bh >> 4, hh = bh & 15;
    const unsigned short* Qb = Q + (size_t)bh * 2048 * 64;
    const unsigned short* Kh = Kg + (size_t)bh * 2048 * 64;
    const unsigned short* Vh = Vt + (size_t)bh * 2048 * 64;

    const int idxb = idx[b];
    const float wgt = (forcing[0] != 0) ? weight[0] : 1.0f;

    // per-lane staging address components (chunk L0 = wave*128 + lane, L1 = L0+64)
    const int L0 = wave * 128 + lane;
    const int rS = L0 >> 3;                      // row (key for K, d for V), second instr +8
    const int cS = (L0 & 7) ^ (rS & 7);          // swizzled global chunk
    // LDS dest base (wave-uniform): chunk (wave*128 + j*64), ushort index = chunk*8
    unsigned short* ldsK0 = &Ks[0][0];           // buffer base chosen in loop
    const int ldsOffJ0 = (wave * 128) * 8;       // +lane*16B handled by HW
    const int ldsOffJ1 = (wave * 128 + 64) * 8;

    #pragma unroll
    for (int ti = 0; ti < 2; ++ti) {
        const int t = (ti == 0) ? p : 31 - p;
        const int q0 = t * 64 + wave * 16;

        short8 aq0 = *(const short8*)&Qb[(q0 + l15) * 64 + quad * 8];
        short8 aq1 = *(const short8*)&Qb[(q0 + l15) * 64 + 32 + quad * 8];

        float m[4], l[4];
        f32x4 o[4] = {};
        #pragma unroll
        for (int r = 0; r < 4; ++r) { m[r] = -3.0e38f; l[r] = 0.0f; }

        const int nkb = t + 1;  // 64-key blocks (causal: keys 0..t*64+63)

        // prologue: stage block 0 into buf 0
        {
            const unsigned short* kg = Kh + (size_t)rS * 64 + cS * 8;
            const unsigned short* vg = Vh + (size_t)rS * 2048 + cS * 8;
            gl_lds16(kg,            &Ks[0][ldsOffJ0]);
            gl_lds16(kg + 8 * 64,   &Ks[0][ldsOffJ1]);
            gl_lds16(vg,            &Vs[0][ldsOffJ0]);
            gl_lds16(vg + 8 * 2048, &Vs[0][ldsOffJ1]);
        }
        __syncthreads();

        for (int kb = 0; kb < nkb; ++kb) {
            const int cur = kb & 1;
            const int kbase = kb * 64;
            if (kb + 1 < nkb) {  // prefetch next block into other buffer
                const int nb = kbase + 64;
                const unsigned short* kg = Kh + (size_t)(nb + rS) * 64 + cS * 8;
                const unsigned short* vg = Vh + (size_t)rS * 2048 + nb + cS * 8;
                gl_lds16(kg,            &Ks[cur ^ 1][ldsOffJ0]);
                gl_lds16(kg + 8 * 64,   &Ks[cur ^ 1][ldsOffJ1]);
                gl_lds16(vg,            &Vs[cur ^ 1][ldsOffJ0]);
                gl_lds16(vg + 8 * 2048, &Vs[cur ^ 1][ldsOffJ1]);
            }

            // ---- S = Q K^T for 4 key sub-tiles of 16 ----
            f32x4 s4[4];
            #pragma unroll
            for (int kt = 0; kt < 4; ++kt) {
                const int row = kt * 16 + l15;
                short8 k0 = *(const short8*)&Ks[cur][row * 64 + ((quad ^ (l15 & 7)) * 8)];
                short8 k1 = *(const short8*)&Ks[cur][row * 64 + (((4 + quad) ^ (l15 & 7)) * 8)];
                f32x4 z = {};
                z = MFMA_B16(aq0, k0, z);
                z = MFMA_B16(aq1, k1, z);
                s4[kt] = z;
            }

            // ---- online softmax over 64 keys ----
            float af[4];
            int kc[4];
            #pragma unroll
            for (int kt = 0; kt < 4; ++kt) {
                kc[kt] = kbase + kt * 16 + l15;
                af[kt] = (kc[kt] >= idxb) ? wgt : 1.0f;
            }
            float alpha[4];
            float pv[4][4];
            #pragma unroll
            for (int r = 0; r < 4; ++r) {
                const int qr = q0 + quad * 4 + r;
                float v0 = (kc[0] <= qr) ? s4[0][r] * 0.125f : -3.0e38f;
                float v1 = (kc[1] <= qr) ? s4[1][r] * 0.125f : -3.0e38f;
                float v2 = (kc[2] <= qr) ? s4[2][r] * 0.125f : -3.0e38f;
                float v3 = (kc[3] <= qr) ? s4[3][r] * 0.125f : -3.0e38f;
                float mm = fmaxf(fmaxf(v0, v1), fmaxf(v2, v3));
                mm = fmaxf(mm, __shfl_xor(mm, 1));
                mm = fmaxf(mm, __shfl_xor(mm, 2));
                mm = fmaxf(mm, __shfl_xor(mm, 4));
                mm = fmaxf(mm, __shfl_xor(mm, 8));
                const float mnew = fmaxf(m[r], mm);
                alpha[r] = __expf(m[r] - mnew);
                m[r] = mnew;
                v0 = __expf(v0 - mnew) * af[0];
                v1 = __expf(v1 - mnew) * af[1];
                v2 = __expf(v2 - mnew) * af[2];
                v3 = __expf(v3 - mnew) * af[3];
                pv[r][0] = v0; pv[r][1] = v1; pv[r][2] = v2; pv[r][3] = v3;
                float rs = (v0 + v1) + (v2 + v3);
                rs += __shfl_xor(rs, 1);
                rs += __shfl_xor(rs, 2);
                rs += __shfl_xor(rs, 4);
                rs += __shfl_xor(rs, 8);
                l[r] = l[r] * alpha[r] + rs;
            }
            #pragma unroll
            for (int d = 0; d < 4; ++d) {
                f32x4 tt = o[d];
                #pragma unroll
                for (int r = 0; r < 4; ++r) tt[r] *= alpha[r];
                o[d] = tt;
            }

            // ---- P: C-layout -> A-layout via per-wave LDS ----
            #pragma unroll
            for (int r = 0; r < 4; ++r)
                #pragma unroll
                for (int kt = 0; kt < 4; ++kt)
                    Plds[wave][(quad * 4 + r) * 68 + kt * 16 + l15] = f2bf(pv[r][kt]);
            short8 ap0 = *(const short8*)&Plds[wave][l15 * 68 + quad * 8];
            short8 ap1 = *(const short8*)&Plds[wave][l15 * 68 + 32 + quad * 8];

            // ---- O += P V ----
            #pragma unroll
            for (int dt = 0; dt < 4; ++dt) {
                const int dr = dt * 16 + l15;
                short8 vf0 = *(const short8*)&Vs[cur][dr * 64 + ((quad ^ (l15 & 7)) * 8)];
                short8 vf1 = *(const short8*)&Vs[cur][dr * 64 + (((4 + quad) ^ (l15 & 7)) * 8)];
                f32x4 oo = o[dt];
                oo = MFMA_B16(ap0, vf0, oo);
                oo = MFMA_B16(ap1, vf1, oo);
                o[dt] = oo;
            }

            __syncthreads();  // all waves done with buf[cur]; prefetch (vmcnt) drained
        }

        // ---- epilogue ----
        #pragma unroll
        for (int r = 0; r < 4; ++r) {
            const int s = q0 + quad * 4 + r;
            const float inv = 1.0f / l[r];
            const size_t rowoff = ((size_t)(b * 2048 + s)) * 1024 + hh * 64;
            #pragma unroll
            for (int d = 0; d < 4; ++d)
                O[rowoff + d * 16 + l15] = f2bf(o[d][r] * inv);
        }
        __syncthreads();  // keep LDS reuse safe across the two tiles
    }
}

extern "C" void kernel_launch(void* const* d_in, const int* in_sizes, int n_in,
                              void* d_out, int out_size, void* d_ws, size_t ws_size,
                              hipStream_t stream) {
    const float* x        = (const float*)d_in[0];   // [2,2048,1024]
    const int*   idx      = (const int*)d_in[1];     // [2]
    const float* weight   = (const float*)d_in[2];   // [1]
    const int*   forcing  = (const int*)d_in[3];     // [1]
    const float* w_qkv    = (const float*)d_in[4];   // [1024,3072]
    const float* b_qkv    = (const float*)d_in[5];   // [3072]
    const float* w_proj   = (const float*)d_in[6];   // [1024,1024]
    const float* b_proj   = (const float*)d_in[7];   // [1024]
    float* out = (float*)d_out;

    char* ws = (char*)d_ws;
    unsigned short* xb      = (unsigned short*)(ws);                   // 8 MB (reused as attn_out)
    unsigned short* wqkvT   = (unsigned short*)(ws + 8388608);         // 6 MB
    unsigned short* wprojT  = (unsigned short*)(ws + 14680064);        // 2 MB
    unsigned short* qbuf    = (unsigned short*)(ws + 16777216);        // 8 MB
    unsigned short* kbuf    = (unsigned short*)(ws + 25165824);        // 8 MB
    unsigned short* vbuf    = (unsigned short*)(ws + 33554432);        // 8 MB
    unsigned short* vTbuf   = (unsigned short*)(ws + 41943040);        // 8 MB (total 48 MB)
    unsigned short* attn_out = xb;  // xb dead after gemm_qkv

    convert_x_kernel<<<4096, 256, 0, stream>>>((const float4*)x, (ushort4*)xb);
    transpose_cvt_kernel<<<dim3(96, 32), dim3(32, 8), 0, stream>>>(w_qkv, wqkvT, 1024, 3072);
    transpose_cvt_kernel<<<dim3(32, 32), dim3(32, 8), 0, stream>>>(w_proj, wprojT, 1024, 1024);
    gemm_qkv_kernel<<<dim3(24, 32), 256, 0, stream>>>(xb, wqkvT, b_qkv, qbuf, kbuf, vbuf);
    transpose_v_kernel<<<dim3(2, 64, 32), dim3(32, 8), 0, stream>>>(vbuf, vTbuf);
    attn_kernel<<<512, 256, 0, stream>>>(qbuf, kbuf, vTbuf, idx, weight, forcing, attn_out);
    gemm_proj_kernel<<<dim3(8, 32), 256, 0, stream>>>(attn_out, wprojT, b_proj, out);
}

// Round 3
// 213.512 us; speedup vs baseline: 1.8893x; 1.2005x over previous
//
#include <hip/hip_runtime.h>

// MultiHeadAttention: B=2,S=2048,D=1024,H=16,dh=64. fp32 in/out, bf16 MFMA internally.
// R3: (1) attention in transposed space (S^T = K Q^T) -> in-register softmax rows,
//     P^T stays in registers (pk_bf16 + shfl), O^T accumulation, LDS-transpose epilogue;
//     balanced bid->tile map + XCD-local bh grouping; Q pre-scaled by 1/8 in QKV epilogue.
// (2) GEMMs upgraded to m97 structure: BK=64, global_load_lds width=16, XOR swizzle.

typedef __attribute__((ext_vector_type(8))) short short8;
typedef __attribute__((ext_vector_type(4))) float f32x4;

#define MFMA_B16(a, b, c) __builtin_amdgcn_mfma_f32_16x16x32_bf16(a, b, c, 0, 0, 0)

static __device__ __forceinline__ unsigned short f2bf(float f) {
    union { float f; unsigned int u; } v;
    v.f = f;
    unsigned int r = (v.u + 0x7fffu + ((v.u >> 16) & 1u)) >> 16;
    return (unsigned short)r;
}

static __device__ __forceinline__ unsigned int pk_bf16(float a, float b) {
#if __has_builtin(__builtin_amdgcn_cvt_pk_bf16_f32)
    typedef __bf16 bf2 __attribute__((ext_vector_type(2)));
    union { bf2 v; unsigned int u; } c;
    c.v = __builtin_amdgcn_cvt_pk_bf16_f32(a, b);
    return c.u;
#else
    return (unsigned int)f2bf(a) | ((unsigned int)f2bf(b) << 16);
#endif
}

static __device__ __forceinline__ void gl_lds16(const void* g, void* l) {
    __builtin_amdgcn_global_load_lds(
        (const __attribute__((address_space(1))) unsigned int*)g,
        (__attribute__((address_space(3))) unsigned int*)l, 16, 0, 0);
}

// ---------------- convert x (fp32 -> bf16) ----------------
__global__ __launch_bounds__(256) void convert_x_kernel(const float4* __restrict__ x,
                                                        ushort4* __restrict__ xb) {
    int i = blockIdx.x * 256 + threadIdx.x;
    float4 v = x[i];
    ushort4 o;
    o.x = f2bf(v.x); o.y = f2bf(v.y); o.z = f2bf(v.z); o.w = f2bf(v.w);
    xb[i] = o;
}

// ------------- transpose+convert: fp32 [R][C] -> bf16 [C][R] -------------
__global__ __launch_bounds__(256) void transpose_cvt_kernel(const float* __restrict__ in,
                                                            unsigned short* __restrict__ out,
                                                            int R, int C) {
    __shared__ float t[32][33];
    int c0 = blockIdx.x * 32, r0 = blockIdx.y * 32;
    int x = threadIdx.x, y = threadIdx.y;
    #pragma unroll
    for (int yy = y; yy < 32; yy += 8)
        t[yy][x] = in[(size_t)(r0 + yy) * C + (c0 + x)];
    __syncthreads();
    #pragma unroll
    for (int yy = y; yy < 32; yy += 8)
        out[(size_t)(c0 + yy) * R + (r0 + x)] = f2bf(t[x][yy]);
}

// ------------- transpose V: [32 bh][2048 s][64 d] -> [32 bh][64 d][2048 s] -------------
__global__ __launch_bounds__(256) void transpose_v_kernel(const unsigned short* __restrict__ v,
                                                          unsigned short* __restrict__ vT) {
    __shared__ unsigned short t[32][33];
    int d0 = blockIdx.x * 32, s0 = blockIdx.y * 32, bh = blockIdx.z;
    const unsigned short* vb = v + (size_t)bh * 2048 * 64;
    unsigned short* vTb = vT + (size_t)bh * 2048 * 64;
    int x = threadIdx.x, y = threadIdx.y;
    #pragma unroll
    for (int yy = y; yy < 32; yy += 8)
        t[yy][x] = vb[(s0 + yy) * 64 + d0 + x];
    __syncthreads();
    #pragma unroll
    for (int yy = y; yy < 32; yy += 8)
        vTb[(d0 + yy) * 2048 + s0 + x] = t[x][yy];
}

// ---------------- QKV GEMM (m97 structure): C[4096x3072] = A * Bt^T ----------------
// 128x128 tile, BK=64, global_load_lds staging, XOR-swizzled LDS (chunk ^ (row&7)).
__global__ __launch_bounds__(256) void gemm_qkv_kernel(const unsigned short* __restrict__ A,
                                                       const unsigned short* __restrict__ Bt,
                                                       const float* __restrict__ bias,
                                                       unsigned short* __restrict__ q,
                                                       unsigned short* __restrict__ k,
                                                       unsigned short* __restrict__ v) {
    __shared__ unsigned short As[128 * 64];
    __shared__ unsigned short Bs[128 * 64];
    const int tid = threadIdx.x;
    const int lane = tid & 63, wave = tid >> 6;
    const int l15 = lane & 15, quad = lane >> 4;
    const int wm = wave >> 1, wn = wave & 1;
    const int row0 = blockIdx.y * 128, col0 = blockIdx.x * 128;
    const int K = 1024;

    // staging: 4 chunks per thread per matrix; dest chunk D linear, source column XOR-swizzled
    int srow[4], scol[4], sdst[4];
    #pragma unroll
    for (int h = 0; h < 4; ++h) {
        int D = h * 256 + wave * 64 + lane;
        srow[h] = D >> 3;
        scol[h] = ((D & 7) ^ (srow[h] & 7)) * 8;
        sdst[h] = (h * 256 + wave * 64) * 8;  // wave-uniform; HW adds lane*16B
    }

    f32x4 acc[4][4] = {};

    for (int kt = 0; kt < K; kt += 64) {
        #pragma unroll
        for (int h = 0; h < 4; ++h) {
            gl_lds16(&A[(size_t)(row0 + srow[h]) * K + kt + scol[h]], &As[sdst[h]]);
            gl_lds16(&Bt[(size_t)(col0 + srow[h]) * K + kt + scol[h]], &Bs[sdst[h]]);
        }
        __syncthreads();
        #pragma unroll
        for (int kk = 0; kk < 2; ++kk) {
            short8 af[4], bf[4];
            #pragma unroll
            for (int i = 0; i < 4; ++i) {
                int r = wm * 64 + i * 16 + l15;
                af[i] = *(const short8*)&As[r * 64 + (((kk * 4 + quad) ^ (r & 7)) * 8)];
            }
            #pragma unroll
            for (int j = 0; j < 4; ++j) {
                int r = wn * 64 + j * 16 + l15;
                bf[j] = *(const short8*)&Bs[r * 64 + (((kk * 4 + quad) ^ (r & 7)) * 8)];
            }
            #pragma unroll
            for (int i = 0; i < 4; ++i)
                #pragma unroll
                for (int j = 0; j < 4; ++j)
                    acc[i][j] = MFMA_B16(af[i], bf[j], acc[i][j]);
        }
        __syncthreads();
    }

    #pragma unroll
    for (int i = 0; i < 4; ++i)
        #pragma unroll
        for (int j = 0; j < 4; ++j)
            #pragma unroll
            for (int r = 0; r < 4; ++r) {
                int row = row0 + wm * 64 + i * 16 + quad * 4 + r;
                int col = col0 + wn * 64 + j * 16 + l15;
                float val = acc[i][j][r] + bias[col];
                int which = col >> 10, rem = col & 1023;
                int hh = rem >> 6, d = rem & 63;
                int b = row >> 11, s = row & 2047;
                size_t o = ((size_t)((b * 16 + hh) * 2048 + s)) * 64 + d;
                if (which == 0) q[o] = f2bf(val * 0.125f);  // fold 1/sqrt(dh), exact pow2
                else if (which == 1) k[o] = f2bf(val);
                else v[o] = f2bf(val);
            }
}

// ---------------- proj GEMM (m97 structure): out[4096x1024] fp32 = A * Bt^T + bias ----------------
// 128x64 tile (512 blocks), BK=64.
__global__ __launch_bounds__(256) void gemm_proj_kernel(const unsigned short* __restrict__ A,
                                                        const unsigned short* __restrict__ Bt,
                                                        const float* __restrict__ bias,
                                                        float* __restrict__ out) {
    __shared__ unsigned short As[128 * 64];
    __shared__ unsigned short Bs[64 * 64];
    const int tid = threadIdx.x;
    const int lane = tid & 63, wave = tid >> 6;
    const int l15 = lane & 15, quad = lane >> 4;
    const int wm = wave >> 1, wn = wave & 1;
    const int row0 = blockIdx.y * 128, col0 = blockIdx.x * 64;
    const int K = 1024;

    int srow[4], scol[4], sdst[4];
    #pragma unroll
    for (int h = 0; h < 4; ++h) {
        int D = h * 256 + wave * 64 + lane;
        srow[h] = D >> 3;
        scol[h] = ((D & 7) ^ (srow[h] & 7)) * 8;
        sdst[h] = (h * 256 + wave * 64) * 8;
    }

    f32x4 acc[4][2] = {};

    for (int kt = 0; kt < K; kt += 64) {
        #pragma unroll
        for (int h = 0; h < 4; ++h)
            gl_lds16(&A[(size_t)(row0 + srow[h]) * K + kt + scol[h]], &As[sdst[h]]);
        #pragma unroll
        for (int h = 0; h < 2; ++h)
            gl_lds16(&Bt[(size_t)(col0 + srow[h]) * K + kt + scol[h]], &Bs[sdst[h]]);
        __syncthreads();
        #pragma unroll
        for (int kk = 0; kk < 2; ++kk) {
            short8 af[4], bf[2];
            #pragma unroll
            for (int i = 0; i < 4; ++i) {
                int r = wm * 64 + i * 16 + l15;
                af[i] = *(const short8*)&As[r * 64 + (((kk * 4 + quad) ^ (r & 7)) * 8)];
            }
            #pragma unroll
            for (int j = 0; j < 2; ++j) {
                int r = wn * 32 + j * 16 + l15;
                bf[j] = *(const short8*)&Bs[r * 64 + (((kk * 4 + quad) ^ (r & 7)) * 8)];
            }
            #pragma unroll
            for (int i = 0; i < 4; ++i)
                #pragma unroll
                for (int j = 0; j < 2; ++j)
                    acc[i][j] = MFMA_B16(af[i], bf[j], acc[i][j]);
        }
        __syncthreads();
    }

    #pragma unroll
    for (int i = 0; i < 4; ++i)
        #pragma unroll
        for (int j = 0; j < 2; ++j)
            #pragma unroll
            for (int r = 0; r < 4; ++r) {
                int row = row0 + wm * 64 + i * 16 + quad * 4 + r;
                int col = col0 + wn * 32 + j * 16 + l15;
                out[(size_t)row * 1024 + col] = acc[i][j][r] + bias[col];
            }
}

// ---------------- flash attention R3 (transposed space) ----------------
// Block = 4 waves = one 64-row q-tile; wave owns 16 q-rows; lane owns q-row l15.
// S^T = K Q^T (C: col=qrow, row=key) -> softmax rows live in registers.
// O^T = V^T P^T accumulated; epilogue transposes through dead K LDS.
__global__ __launch_bounds__(256) void attn_kernel(const unsigned short* __restrict__ Q,
                                                   const unsigned short* __restrict__ Kg,
                                                   const unsigned short* __restrict__ Vt,
                                                   const int* __restrict__ idx,
                                                   const float* __restrict__ weight,
                                                   const int* __restrict__ forcing,
                                                   unsigned short* __restrict__ O) {
    __shared__ unsigned short Ks[2][4096];
    __shared__ unsigned short Vs[2][4096];

    const int tid = threadIdx.x;
    const int lane = tid & 63, wave = tid >> 6;
    const int l15 = lane & 15, quad = lane >> 4;
    const int bid = blockIdx.x;
    // balanced tile map: per-CU iteration sums equal; bh = bid&31 keeps a head on one XCD
    const int u = bid >> 5, a = u & 7, qg = u >> 3;
    const int t = (qg == 0) ? (31 - a) : (qg == 1) ? (16 + a) : (qg == 2) ? (15 - a) : a;
    const int bh = bid & 31;
    const int b = bh >> 4, hh = bh & 15;
    const unsigned short* Qb = Q + (size_t)bh * 2048 * 64;
    const unsigned short* Kh = Kg + (size_t)bh * 2048 * 64;
    const unsigned short* Vh = Vt + (size_t)bh * 2048 * 64;

    const int idxb = idx[b];
    const float wgt = (forcing[0] != 0) ? weight[0] : 1.0f;

    const int L0 = wave * 128 + lane;
    const int rS = L0 >> 3;
    const int cS = (L0 & 7) ^ (rS & 7);
    const int ldsOffJ0 = (wave * 128) * 8;
    const int ldsOffJ1 = (wave * 128 + 64) * 8;

    const int q0 = t * 64 + wave * 16;
    const int qrow = q0 + l15;  // this lane's q-row

    // Q fragment (pre-scaled by 1/8 in QKV epilogue); same data serves as B-operand
    short8 aq0 = *(const short8*)&Qb[(q0 + l15) * 64 + quad * 8];
    short8 aq1 = *(const short8*)&Qb[(q0 + l15) * 64 + 32 + quad * 8];

    float m = -3.0e38f, l = 0.0f;
    f32x4 o[4] = {};

    const int nkb = t + 1;

    {
        const unsigned short* kg = Kh + (size_t)rS * 64 + cS * 8;
        const unsigned short* vg = Vh + (size_t)rS * 2048 + cS * 8;
        gl_lds16(kg,            &Ks[0][ldsOffJ0]);
        gl_lds16(kg + 8 * 64,   &Ks[0][ldsOffJ1]);
        gl_lds16(vg,            &Vs[0][ldsOffJ0]);
        gl_lds16(vg + 8 * 2048, &Vs[0][ldsOffJ1]);
    }
    __syncthreads();

    for (int kb = 0; kb < nkb; ++kb) {
        const int cur = kb & 1;
        const int kbase = kb * 64;
        if (kb + 1 < nkb) {
            const int nb = kbase + 64;
            const unsigned short* kg = Kh + (size_t)(nb + rS) * 64 + cS * 8;
            const unsigned short* vg = Vh + (size_t)rS * 2048 + nb + cS * 8;
            gl_lds16(kg,            &Ks[cur ^ 1][ldsOffJ0]);
            gl_lds16(kg + 8 * 64,   &Ks[cur ^ 1][ldsOffJ1]);
            gl_lds16(vg,            &Vs[cur ^ 1][ldsOffJ0]);
            gl_lds16(vg + 8 * 2048, &Vs[cur ^ 1][ldsOffJ1]);
        }

        // ---- S^T: lane holds keys kbase + kt*16 + quad*4 + r for q-row l15 ----
        f32x4 sT[4];
        #pragma unroll
        for (int kt = 0; kt < 4; ++kt) {
            const int row = kt * 16 + l15;
            short8 k0 = *(const short8*)&Ks[cur][row * 64 + ((quad ^ (row & 7)) * 8)];
            short8 k1 = *(const short8*)&Ks[cur][row * 64 + (((4 + quad) ^ (row & 7)) * 8)];
            f32x4 z = {};
            z = MFMA_B16(k0, aq0, z);
            z = MFMA_B16(k1, aq1, z);
            sT[kt] = z;
        }

        // ---- causal mask: only the diagonal block needs it ----
        if (kb == t) {
            #pragma unroll
            for (int kt = 0; kt < 4; ++kt)
                #pragma unroll
                for (int r = 0; r < 4; ++r)
                    if (kbase + kt * 16 + quad * 4 + r > qrow) sT[kt][r] = -3.0e38f;
        }

        // ---- row max: 15 in-reg + 2 shfl ----
        float mloc = fmaxf(fmaxf(fmaxf(sT[0][0], sT[0][1]), fmaxf(sT[0][2], sT[0][3])),
                           fmaxf(fmaxf(sT[1][0], sT[1][1]), fmaxf(sT[1][2], sT[1][3])));
        mloc = fmaxf(mloc, fmaxf(fmaxf(fmaxf(sT[2][0], sT[2][1]), fmaxf(sT[2][2], sT[2][3])),
                                 fmaxf(fmaxf(sT[3][0], sT[3][1]), fmaxf(sT[3][2], sT[3][3]))));
        mloc = fmaxf(mloc, __shfl_xor(mloc, 16));
        mloc = fmaxf(mloc, __shfl_xor(mloc, 32));
        const float mnew = fmaxf(m, mloc);
        const float alpha = __expf(m - mnew);
        m = mnew;

        // ---- p = exp(s - m) * forcing, in place ----
        #pragma unroll
        for (int kt = 0; kt < 4; ++kt)
            #pragma unroll
            for (int r = 0; r < 4; ++r)
                sT[kt][r] = __expf(sT[kt][r] - mnew);
        if (kbase >= idxb) {
            #pragma unroll
            for (int kt = 0; kt < 4; ++kt)
                #pragma unroll
                for (int r = 0; r < 4; ++r) sT[kt][r] *= wgt;
        } else if (kbase + 63 >= idxb) {
            #pragma unroll
            for (int kt = 0; kt < 4; ++kt)
                #pragma unroll
                for (int r = 0; r < 4; ++r)
                    if (kbase + kt * 16 + quad * 4 + r >= idxb) sT[kt][r] *= wgt;
        }

        // ---- row sum: 15 in-reg + 2 shfl ----
        float rs = ((sT[0][0] + sT[0][1]) + (sT[0][2] + sT[0][3])) +
                   ((sT[1][0] + sT[1][1]) + (sT[1][2] + sT[1][3])) +
                   ((sT[2][0] + sT[2][1]) + (sT[2][2] + sT[2][3])) +
                   ((sT[3][0] + sT[3][1]) + (sT[3][2] + sT[3][3]));
        rs += __shfl_xor(rs, 16);
        rs += __shfl_xor(rs, 32);
        l = l * alpha + rs;

        // ---- rescale O^T ----
        #pragma unroll
        for (int dt = 0; dt < 4; ++dt) {
            f32x4 tt = o[dt];
            #pragma unroll
            for (int r = 0; r < 4; ++r) tt[r] *= alpha;
            o[dt] = tt;
        }

        // ---- pack P^T to bf16 pairs ----
        unsigned int plo[4], phi[4];
        #pragma unroll
        for (int kt = 0; kt < 4; ++kt) {
            plo[kt] = pk_bf16(sT[kt][0], sT[kt][1]);
            phi[kt] = pk_bf16(sT[kt][2], sT[kt][3]);
        }

        // ---- O^T += V^T P^T: B-frag built via shfl (keys ka*32 + quad*8 .. +7) ----
        #pragma unroll
        for (int ka = 0; ka < 2; ++ka) {
            const int srcA = ((quad & 1) * 32) + l15;
            const int srcB = srcA + 16;
            unsigned int tA0 = __shfl(plo[ka * 2], srcA), tA1 = __shfl(plo[ka * 2 + 1], srcA);
            unsigned int hA0 = __shfl(phi[ka * 2], srcA), hA1 = __shfl(phi[ka * 2 + 1], srcA);
            unsigned int tB0 = __shfl(plo[ka * 2], srcB), tB1 = __shfl(plo[ka * 2 + 1], srcB);
            unsigned int hB0 = __shfl(phi[ka * 2], srcB), hB1 = __shfl(phi[ka * 2 + 1], srcB);
            const bool hi = quad >= 2;
            union { short8 v; unsigned int u[4]; } pf;
            pf.u[0] = hi ? tA1 : tA0;
            pf.u[1] = hi ? hA1 : hA0;
            pf.u[2] = hi ? tB1 : tB0;
            pf.u[3] = hi ? hB1 : hB0;
            #pragma unroll
            for (int dt = 0; dt < 4; ++dt) {
                const int row = dt * 16 + l15;
                short8 vf = *(const short8*)&Vs[cur][row * 64 + (((ka * 4 + quad) ^ (row & 7)) * 8)];
                o[dt] = MFMA_B16(vf, pf.v, o[dt]);
            }
        }

        __syncthreads();
    }

    // ---- epilogue: O^T -> O via LDS transpose (K buffers are dead) ----
    const float inv = 1.0f / l;
    unsigned short* sc = &Ks[0][0] + wave * 1152;  // 16 rows x 72 stride
    #pragma unroll
    for (int dt = 0; dt < 4; ++dt)
        #pragma unroll
        for (int r = 0; r < 4; ++r)
            sc[l15 * 72 + dt * 16 + quad * 4 + r] = f2bf(o[dt][r] * inv);
    const size_t rowoff = ((size_t)(b * 2048 + q0 + l15)) * 1024 + hh * 64;
    #pragma unroll
    for (int h = 0; h < 2; ++h) {
        short8 v8 = *(const short8*)&sc[l15 * 72 + quad * 16 + h * 8];
        *(short8*)&O[rowoff + quad * 16 + h * 8] = v8;
    }
}

extern "C" void kernel_launch(void* const* d_in, const int* in_sizes, int n_in,
                              void* d_out, int out_size, void* d_ws, size_t ws_size,
                              hipStream_t stream) {
    const float* x        = (const float*)d_in[0];
    const int*   idx      = (const int*)d_in[1];
    const float* weight   = (const float*)d_in[2];
    const int*   forcing  = (const int*)d_in[3];
    const float* w_qkv    = (const float*)d_in[4];
    const float* b_qkv    = (const float*)d_in[5];
    const float* w_proj   = (const float*)d_in[6];
    const float* b_proj   = (const float*)d_in[7];
    float* out = (float*)d_out;

    char* ws = (char*)d_ws;
    unsigned short* xb      = (unsigned short*)(ws);              // 8 MB (reused as attn_out)
    unsigned short* wqkvT   = (unsigned short*)(ws + 8388608);    // 6 MB
    unsigned short* wprojT  = (unsigned short*)(ws + 14680064);   // 2 MB
    unsigned short* qbuf    = (unsigned short*)(ws + 16777216);   // 8 MB
    unsigned short* kbuf    = (unsigned short*)(ws + 25165824);   // 8 MB
    unsigned short* vbuf    = (unsigned short*)(ws + 33554432);   // 8 MB
    unsigned short* vTbuf   = (unsigned short*)(ws + 41943040);   // 8 MB (total 48 MB)
    unsigned short* attn_out = xb;

    convert_x_kernel<<<4096, 256, 0, stream>>>((const float4*)x, (ushort4*)xb);
    transpose_cvt_kernel<<<dim3(96, 32), dim3(32, 8), 0, stream>>>(w_qkv, wqkvT, 1024, 3072);
    transpose_cvt_kernel<<<dim3(32, 32), dim3(32, 8), 0, stream>>>(w_proj, wprojT, 1024, 1024);
    gemm_qkv_kernel<<<dim3(24, 32), 256, 0, stream>>>(xb, wqkvT, b_qkv, qbuf, kbuf, vbuf);
    transpose_v_kernel<<<dim3(2, 64, 32), dim3(32, 8), 0, stream>>>(vbuf, vTbuf);
    attn_kernel<<<1024, 256, 0, stream>>>(qbuf, kbuf, vTbuf, idx, weight, forcing, attn_out);
    gemm_proj_kernel<<<dim3(16, 32), 256, 0, stream>>>(attn_out, wprojT, b_proj, out);
}